// Round 1
// baseline (5386.995 us; speedup 1.0000x reference)
//
#include <hip/hip_runtime.h>

#define NB 2
#define N_C 16384
#define N_F 65536
#define E_C 65536
#define E_F 262144

__global__ void build_inv(const int* __restrict__ idx, int* __restrict__ inv, int n) {
    int i = blockIdx.x * blockDim.x + threadIdx.x;
    if (i < n) inv[idx[i]] = i;
}

// One block of COUT threads per (batch, edge).
// xin: (NB, n_in_rows, CIN) rows indexed through inv (if non-null) else directly.
// out: (NB, n_out_rows, COUT), accumulated with atomics (segment_sum over dst).
template <int CIN, int COUT>
__launch_bounds__(COUT) __global__
void edgeconv(const float* __restrict__ xin, int bs_in,
              const int* __restrict__ inv,
              const int* __restrict__ ei, int E,
              const float* __restrict__ W1, const float* __restrict__ b1,
              const float* __restrict__ W2, const float* __restrict__ b2,
              const float* __restrict__ g, const float* __restrict__ bt,
              float* __restrict__ out, int bs_out) {
    __shared__ float feat[2 * CIN];
    __shared__ float h1s[COUT];
    __shared__ float red[4];

    const int bid = blockIdx.x;
    const int b = bid / E;
    const int e = bid - b * E;
    const int src = ei[e];
    const int dst = ei[E + e];
    const int j = threadIdx.x;

    int si = src, di = dst;
    if (inv) { si = inv[src]; di = inv[dst]; }
    const float* xs = xin + (size_t)b * bs_in + (size_t)si * CIN;
    const float* xd = xin + (size_t)b * bs_in + (size_t)di * CIN;

    for (int k = j; k < CIN; k += COUT) {
        float vd = (di >= 0) ? xd[k] : 0.f;
        float vs = (si >= 0) ? xs[k] : 0.f;
        feat[k] = vd;
        feat[CIN + k] = vs - vd;
    }
    __syncthreads();

    // layer 1: h1 = relu(feat @ W1 + b1)
    float a0 = 0.f, a1 = 0.f, a2 = 0.f, a3 = 0.f;
    for (int k = 0; k < 2 * CIN; k += 4) {
        a0 = fmaf(feat[k + 0], W1[(k + 0) * COUT + j], a0);
        a1 = fmaf(feat[k + 1], W1[(k + 1) * COUT + j], a1);
        a2 = fmaf(feat[k + 2], W1[(k + 2) * COUT + j], a2);
        a3 = fmaf(feat[k + 3], W1[(k + 3) * COUT + j], a3);
    }
    float h = (a0 + a1) + (a2 + a3) + b1[j];
    h1s[j] = fmaxf(h, 0.f);
    __syncthreads();

    // layer 2: v = h1 @ W2 + b2
    a0 = a1 = a2 = a3 = 0.f;
    for (int k = 0; k < COUT; k += 4) {
        a0 = fmaf(h1s[k + 0], W2[(k + 0) * COUT + j], a0);
        a1 = fmaf(h1s[k + 1], W2[(k + 1) * COUT + j], a1);
        a2 = fmaf(h1s[k + 2], W2[(k + 2) * COUT + j], a2);
        a3 = fmaf(h1s[k + 3], W2[(k + 3) * COUT + j], a3);
    }
    float v = (a0 + a1) + (a2 + a3) + b2[j];

    // layernorm over COUT channels
    float s = v, s2 = v * v;
    #pragma unroll
    for (int off = 32; off >= 1; off >>= 1) {
        s  += __shfl_xor(s, off, 64);
        s2 += __shfl_xor(s2, off, 64);
    }
    float mu, var;
    constexpr int NW = COUT / 64;
    if constexpr (NW == 1) {
        mu = s / COUT;
        var = s2 / COUT - mu * mu;
    } else {
        const int w = j >> 6;
        if ((j & 63) == 0) { red[2 * w] = s; red[2 * w + 1] = s2; }
        __syncthreads();
        float ts = red[0] + red[2];
        float ts2 = red[1] + red[3];
        mu = ts / COUT;
        var = ts2 / COUT - mu * mu;
    }
    float rstd = rsqrtf(var + 1e-5f);
    float ov = (v - mu) * rstd * g[j] + bt[j];

    atomicAdd(out + (size_t)b * bs_out + (size_t)dst * COUT + j, ov);
}

__global__ void leaky_kernel(float* __restrict__ out, int n) {
    int i = blockIdx.x * blockDim.x + threadIdx.x;
    if (i < n) {
        float v = out[i];
        out[i] = v > 0.f ? v : 0.01f * v;
    }
}

extern "C" void kernel_launch(void* const* d_in, const int* in_sizes, int n_in,
                              void* d_out, int out_size, void* d_ws, size_t ws_size,
                              hipStream_t stream) {
    const float* x    = (const float*)d_in[0];
    const int*   idx  = (const int*)d_in[1];
    const int*   ei_c = (const int*)d_in[2];
    const int*   ei_f = (const int*)d_in[3];
    const float* sW1 = (const float*)d_in[4];
    const float* sb1 = (const float*)d_in[5];
    const float* sW2 = (const float*)d_in[6];
    const float* sb2 = (const float*)d_in[7];
    const float* sg  = (const float*)d_in[8];
    const float* sbt = (const float*)d_in[9];
    const float* aW1 = (const float*)d_in[10];
    const float* ab1 = (const float*)d_in[11];
    const float* aW2 = (const float*)d_in[12];
    const float* ab2 = (const float*)d_in[13];
    const float* ag  = (const float*)d_in[14];
    const float* abt = (const float*)d_in[15];
    const float* bW1 = (const float*)d_in[16];
    const float* bb1 = (const float*)d_in[17];
    const float* bW2 = (const float*)d_in[18];
    const float* bb2 = (const float*)d_in[19];
    const float* bg  = (const float*)d_in[20];
    const float* bbt = (const float*)d_in[21];

    float* out = (float*)d_out;
    int*   inv = (int*)d_ws;
    float* h_a = (float*)((char*)d_ws + (size_t)N_F * sizeof(int));

    hipMemsetAsync(inv, 0xFF, (size_t)N_F * sizeof(int), stream);
    hipMemsetAsync(h_a, 0, (size_t)NB * N_C * 64 * sizeof(float), stream);
    hipMemsetAsync(d_out, 0, (size_t)out_size * sizeof(float), stream);

    build_inv<<<N_C / 256, 256, 0, stream>>>(idx, inv, N_C);

    // skip = edgeconv(unpool(x), ei_f, s-params) -> accumulate into out
    edgeconv<128, 128><<<NB * E_F, 128, 0, stream>>>(
        x, N_C * 128, inv, ei_f, E_F, sW1, sb1, sW2, sb2, sg, sbt, out, N_F * 128);

    // h = edgeconv(x, ei_c, a-params) -> h_a (NB, N_C, 64)
    edgeconv<128, 64><<<NB * E_C, 64, 0, stream>>>(
        x, N_C * 128, nullptr, ei_c, E_C, aW1, ab1, aW2, ab2, ag, abt, h_a, N_C * 64);

    // h = edgeconv(unpool(h_a), ei_f, b-params) -> accumulate into out
    edgeconv<64, 128><<<NB * E_F, 128, 0, stream>>>(
        h_a, N_C * 64, inv, ei_f, E_F, bW1, bb1, bW2, bb2, bg, bbt, out, N_F * 128);

    leaky_kernel<<<(NB * N_F * 128) / 256, 256, 0, stream>>>(out, NB * N_F * 128);
}

// Round 2
// 2007.070 us; speedup vs baseline: 2.6840x; 2.6840x over previous
//
#include <hip/hip_runtime.h>

typedef _Float16 half8 __attribute__((ext_vector_type(8)));
typedef _Float16 half4v __attribute__((ext_vector_type(4)));
typedef float f32x4 __attribute__((ext_vector_type(4)));

#define NB 2
#define N_C 16384
#define N_F 65536
#define E_C 65536
#define E_F 262144

__global__ void build_inv(const int* __restrict__ idx, int* __restrict__ inv, int n) {
    int i = blockIdx.x * blockDim.x + threadIdx.x;
    if (i < n) inv[idx[i]] = i;
}

// Repack W (K x N, fp32, row-major) into MFMA B-fragment order, fp16.
// Fragment f = kt*(N/16)+nt holds 64 lanes x 8 halfs:
//   Ws[(f*64+lane)*8+j] = W[kt*32 + (lane>>4)*8 + j][nt*16 + (lane&15)]
__global__ void swizzle_w(const float* __restrict__ W, _Float16* __restrict__ Ws, int K, int N) {
    int o = blockIdx.x * blockDim.x + threadIdx.x;
    if (o >= K * N) return;
    int j = o & 7;
    int lane = (o >> 3) & 63;
    int frag = o >> 9;
    int ntiles = N >> 4;
    int nt = frag % ntiles;
    int kt = frag / ntiles;
    int k = kt * 32 + (lane >> 4) * 8 + j;
    int n = nt * 16 + (lane & 15);
    Ws[o] = (_Float16)W[k * N + n];
}

// One block = 64 edges. 256 threads = 4 waves; wave w computes cols [w*COUT/4, (w+1)*COUT/4).
template <int CIN, int COUT>
__launch_bounds__(256, 3) __global__
void edge_mfma(const float* __restrict__ xin, int bs_in,
               const int* __restrict__ inv,
               const int* __restrict__ ei, int E,
               const _Float16* __restrict__ W1s, const float* __restrict__ b1,
               const _Float16* __restrict__ W2s, const float* __restrict__ b2,
               const float* __restrict__ g, const float* __restrict__ bt,
               float* __restrict__ out, int bs_out) {
    constexpr int K1 = 2 * CIN;
    constexpr int FPITCH = K1 + 8;    // halfs; row stride multiple of 16B for b128 reads
    constexpr int HPITCH = COUT + 8;  // halfs
    constexpr int VPITCH = COUT + 1;  // floats; odd pitch for LN bank spread
    constexpr int NPW = COUT / 4;     // cols per wave
    constexpr int NT = NPW / 16;      // 16-col tiles per wave
    constexpr int FEAT_BYTES = 64 * FPITCH * 2;
    constexpr int V_BYTES = 64 * VPITCH * 4;
    constexpr int U_BYTES = FEAT_BYTES > V_BYTES ? FEAT_BYTES : V_BYTES;

    __shared__ __align__(16) char smemU[U_BYTES];     // feat (GEMM1) then v (LN) — feat dead after GEMM1
    __shared__ __align__(16) _Float16 h1L[64 * HPITCH];
    __shared__ int sidx[64], didx[64], dstl[64];

    _Float16* featL = (_Float16*)smemU;
    float* vL = (float*)smemU;

    const int t = threadIdx.x;
    const int eb = blockIdx.x * 64;
    const int b = eb / E;
    const int e0 = eb - b * E;

    if (t < 64) {
        int s = ei[e0 + t];
        int d = ei[E + e0 + t];
        dstl[t] = d;
        if (inv) { s = inv[s]; d = inv[d]; }
        sidx[t] = s;
        didx[t] = d;
    }
    __syncthreads();

    // ---- gather: 4 threads per edge, fp32 -> fp16 [xd, xs-xd] ----
    {
        const int m = t >> 2, l4 = t & 3;
        const int si = sidx[m], di = didx[m];
        const float* base = xin + (size_t)b * bs_in;
        #pragma unroll
        for (int i = 0; i < CIN / 16; ++i) {
            const int k4 = i * 4 + l4;
            f32x4 xd4 = {0.f, 0.f, 0.f, 0.f};
            f32x4 xs4 = {0.f, 0.f, 0.f, 0.f};
            if (di >= 0) xd4 = *(const f32x4*)(base + (size_t)di * CIN + k4 * 4);
            if (si >= 0) xs4 = *(const f32x4*)(base + (size_t)si * CIN + k4 * 4);
            half4v hd, hs;
            #pragma unroll
            for (int c = 0; c < 4; ++c) {
                hd[c] = (_Float16)xd4[c];
                hs[c] = (_Float16)(xs4[c] - xd4[c]);
            }
            *(half4v*)(featL + m * FPITCH + k4 * 4) = hd;
            *(half4v*)(featL + m * FPITCH + CIN + k4 * 4) = hs;
        }
    }
    __syncthreads();

    const int wv = t >> 6, lane = t & 63;
    const int q = lane >> 4, lm = lane & 15;
    const int n0 = wv * NPW;
    const f32x4 zero4 = {0.f, 0.f, 0.f, 0.f};

    f32x4 acc[4][NT];
    #pragma unroll
    for (int mt = 0; mt < 4; ++mt)
        #pragma unroll
        for (int nt = 0; nt < NT; ++nt) acc[mt][nt] = zero4;

    // ---- GEMM1: h1 = relu(feat @ W1 + b1) ----
    #pragma unroll
    for (int kt = 0; kt < K1 / 32; ++kt) {
        half8 a[4];
        #pragma unroll
        for (int mt = 0; mt < 4; ++mt)
            a[mt] = *(const half8*)(featL + (mt * 16 + lm) * FPITCH + kt * 32 + q * 8);
        #pragma unroll
        for (int nt = 0; nt < NT; ++nt) {
            half8 bf = *(const half8*)(W1s + ((size_t)(kt * (COUT / 16) + wv * NT + nt) * 64 + lane) * 8);
            #pragma unroll
            for (int mt = 0; mt < 4; ++mt)
                acc[mt][nt] = __builtin_amdgcn_mfma_f32_16x16x32_f16(a[mt], bf, acc[mt][nt], 0, 0, 0);
        }
    }

    #pragma unroll
    for (int nt = 0; nt < NT; ++nt) {
        const float b1v = b1[n0 + nt * 16 + lm];
        #pragma unroll
        for (int mt = 0; mt < 4; ++mt)
            #pragma unroll
            for (int r = 0; r < 4; ++r) {
                float val = acc[mt][nt][r] + b1v;
                h1L[(mt * 16 + q * 4 + r) * HPITCH + n0 + nt * 16 + lm] = (_Float16)fmaxf(val, 0.f);
            }
    }
    __syncthreads();  // h1 ready; also: all waves done reading feat -> v may overwrite it

    // ---- GEMM2: v = h1 @ W2 + b2 ----
    #pragma unroll
    for (int mt = 0; mt < 4; ++mt)
        #pragma unroll
        for (int nt = 0; nt < NT; ++nt) acc[mt][nt] = zero4;

    #pragma unroll
    for (int kt = 0; kt < COUT / 32; ++kt) {
        half8 a[4];
        #pragma unroll
        for (int mt = 0; mt < 4; ++mt)
            a[mt] = *(const half8*)(h1L + (mt * 16 + lm) * HPITCH + kt * 32 + q * 8);
        #pragma unroll
        for (int nt = 0; nt < NT; ++nt) {
            half8 bf = *(const half8*)(W2s + ((size_t)(kt * (COUT / 16) + wv * NT + nt) * 64 + lane) * 8);
            #pragma unroll
            for (int mt = 0; mt < 4; ++mt)
                acc[mt][nt] = __builtin_amdgcn_mfma_f32_16x16x32_f16(a[mt], bf, acc[mt][nt], 0, 0, 0);
        }
    }

    #pragma unroll
    for (int nt = 0; nt < NT; ++nt) {
        const float b2v = b2[n0 + nt * 16 + lm];
        #pragma unroll
        for (int mt = 0; mt < 4; ++mt)
            #pragma unroll
            for (int r = 0; r < 4; ++r)
                vL[(mt * 16 + q * 4 + r) * VPITCH + n0 + nt * 16 + lm] = acc[mt][nt][r] + b2v;
    }
    __syncthreads();

    // ---- LayerNorm (4 threads/row) + atomic scatter ----
    {
        const int r = t >> 2, p = t & 3;
        float s = 0.f, s2 = 0.f;
        #pragma unroll
        for (int i = 0; i < COUT / 4; ++i) {
            float val = vL[r * VPITCH + p + 4 * i];
            s += val;
            s2 += val * val;
        }
        s  += __shfl_xor(s, 1, 64);  s2 += __shfl_xor(s2, 1, 64);
        s  += __shfl_xor(s, 2, 64);  s2 += __shfl_xor(s2, 2, 64);
        const float mu = s * (1.f / COUT);
        const float var = s2 * (1.f / COUT) - mu * mu;
        const float rstd = rsqrtf(var + 1e-5f);
        const int dst = dstl[r];
        float* obase = out + (size_t)b * bs_out + (size_t)dst * COUT;
        #pragma unroll
        for (int i = 0; i < COUT / 4; ++i) {
            const int n = p + 4 * i;
            float val = (vL[r * VPITCH + n] - mu) * rstd * g[n] + bt[n];
            atomicAdd(obase + n, val);
        }
    }
}

__global__ void leaky_kernel(float* __restrict__ out, int n4) {
    int i = blockIdx.x * blockDim.x + threadIdx.x;
    if (i < n4) {
        f32x4 v = ((f32x4*)out)[i];
        #pragma unroll
        for (int c = 0; c < 4; ++c) v[c] = v[c] > 0.f ? v[c] : 0.01f * v[c];
        ((f32x4*)out)[i] = v;
    }
}

extern "C" void kernel_launch(void* const* d_in, const int* in_sizes, int n_in,
                              void* d_out, int out_size, void* d_ws, size_t ws_size,
                              hipStream_t stream) {
    const float* x    = (const float*)d_in[0];
    const int*   idx  = (const int*)d_in[1];
    const int*   ei_c = (const int*)d_in[2];
    const int*   ei_f = (const int*)d_in[3];
    const float* sW1 = (const float*)d_in[4];
    const float* sb1 = (const float*)d_in[5];
    const float* sW2 = (const float*)d_in[6];
    const float* sb2 = (const float*)d_in[7];
    const float* sg  = (const float*)d_in[8];
    const float* sbt = (const float*)d_in[9];
    const float* aW1 = (const float*)d_in[10];
    const float* ab1 = (const float*)d_in[11];
    const float* aW2 = (const float*)d_in[12];
    const float* ab2 = (const float*)d_in[13];
    const float* ag  = (const float*)d_in[14];
    const float* abt = (const float*)d_in[15];
    const float* bW1 = (const float*)d_in[16];
    const float* bb1 = (const float*)d_in[17];
    const float* bW2 = (const float*)d_in[18];
    const float* bb2 = (const float*)d_in[19];
    const float* bg  = (const float*)d_in[20];
    const float* bbt = (const float*)d_in[21];

    float* out = (float*)d_out;

    // ws layout
    char* ws = (char*)d_ws;
    int*   inv = (int*)ws;                                   // 256 KB
    float* h_a = (float*)(ws + (size_t)N_F * 4);             // 8 MB
    char*  wp  = ws + (size_t)N_F * 4 + (size_t)NB * N_C * 64 * 4;
    _Float16* sW1s = (_Float16*)wp;                wp += 256 * 128 * 2;
    _Float16* sW2s = (_Float16*)wp;                wp += 128 * 128 * 2;
    _Float16* aW1s = (_Float16*)wp;                wp += 256 * 64 * 2;
    _Float16* aW2s = (_Float16*)wp;                wp += 64 * 64 * 2;
    _Float16* bW1s = (_Float16*)wp;                wp += 128 * 128 * 2;
    _Float16* bW2s = (_Float16*)wp;                wp += 128 * 128 * 2;

    hipMemsetAsync(inv, 0xFF, (size_t)N_F * 4, stream);
    hipMemsetAsync(h_a, 0, (size_t)NB * N_C * 64 * 4, stream);
    hipMemsetAsync(d_out, 0, (size_t)out_size * 4, stream);

    build_inv<<<N_C / 256, 256, 0, stream>>>(idx, inv, N_C);

    swizzle_w<<<(256 * 128 + 255) / 256, 256, 0, stream>>>(sW1, sW1s, 256, 128);
    swizzle_w<<<(128 * 128 + 255) / 256, 256, 0, stream>>>(sW2, sW2s, 128, 128);
    swizzle_w<<<(256 * 64 + 255) / 256, 256, 0, stream>>>(aW1, aW1s, 256, 64);
    swizzle_w<<<(64 * 64 + 255) / 256, 256, 0, stream>>>(aW2, aW2s, 64, 64);
    swizzle_w<<<(128 * 128 + 255) / 256, 256, 0, stream>>>(bW1, bW1s, 128, 128);
    swizzle_w<<<(128 * 128 + 255) / 256, 256, 0, stream>>>(bW2, bW2s, 128, 128);

    // skip = edgeconv(unpool(x), ei_f, s-params) -> accumulate into out
    edge_mfma<128, 128><<<NB * E_F / 64, 256, 0, stream>>>(
        x, N_C * 128, inv, ei_f, E_F, sW1s, sb1, sW2s, sb2, sg, sbt, out, N_F * 128);

    // h_a = edgeconv(x, ei_c, a-params)
    edge_mfma<128, 64><<<NB * E_C / 64, 256, 0, stream>>>(
        x, N_C * 128, nullptr, ei_c, E_C, aW1s, ab1, aW2s, ab2, ag, abt, h_a, N_C * 64);

    // out += edgeconv(unpool(h_a), ei_f, b-params)
    edge_mfma<64, 128><<<NB * E_F / 64, 256, 0, stream>>>(
        h_a, N_C * 64, inv, ei_f, E_F, bW1s, bb1, bW2s, bb2, bg, bbt, out, N_F * 128);

    leaky_kernel<<<(NB * N_F * 128 / 4 + 255) / 256, 256, 0, stream>>>(out, NB * N_F * 128 / 4);
}

// Round 3
// 624.667 us; speedup vs baseline: 8.6238x; 3.2130x over previous
//
#include <hip/hip_runtime.h>

typedef _Float16 half8  __attribute__((ext_vector_type(8)));
typedef _Float16 half4v __attribute__((ext_vector_type(4)));
typedef _Float16 half2v __attribute__((ext_vector_type(2)));
typedef float    f32x4  __attribute__((ext_vector_type(4)));
typedef float    f32x2  __attribute__((ext_vector_type(2)));

#define NB 2
#define N_C 16384
#define N_F 65536
#define E_C 65536
#define E_F 262144

__global__ void build_inv(const int* __restrict__ idx, int* __restrict__ inv, int n) {
    int i = blockIdx.x * blockDim.x + threadIdx.x;
    if (i < n) inv[idx[i]] = i;
}

// Repack W (K x N, fp32, row-major) into MFMA B-fragment order, fp16.
__global__ void swizzle_w(const float* __restrict__ W, _Float16* __restrict__ Ws, int K, int N) {
    int o = blockIdx.x * blockDim.x + threadIdx.x;
    if (o >= K * N) return;
    int j = o & 7;
    int lane = (o >> 3) & 63;
    int frag = o >> 9;
    int ntiles = N >> 4;
    int nt = frag % ntiles;
    int kt = frag / ntiles;
    int k = kt * 32 + (lane >> 4) * 8 + j;
    int n = nt * 16 + (lane & 15);
    Ws[o] = (_Float16)W[k * N + n];
}

// ---------- counting sort of edges by dst ----------
__global__ void hist_dst(const int* __restrict__ ei, int E, int* __restrict__ cnt) {
    int e = blockIdx.x * 256 + threadIdx.x;
    if (e < E) atomicAdd(&cnt[ei[E + e]], 1);
}

__global__ void scan_chunk_sums(const int* __restrict__ cnt, int* __restrict__ csum) {
    __shared__ int red[4];
    int v = cnt[blockIdx.x * 256 + threadIdx.x];
    #pragma unroll
    for (int off = 32; off >= 1; off >>= 1) v += __shfl_xor(v, off, 64);
    if ((threadIdx.x & 63) == 0) red[threadIdx.x >> 6] = v;
    __syncthreads();
    if (threadIdx.x == 0) csum[blockIdx.x] = red[0] + red[1] + red[2] + red[3];
}

__global__ void scan_base(const int* __restrict__ csum, int* __restrict__ cbase, int n) {
    __shared__ int buf[256];
    int t = threadIdx.x;
    buf[t] = (t < n) ? csum[t] : 0;
    __syncthreads();
    for (int off = 1; off < 256; off <<= 1) {
        int v = (t >= off) ? buf[t - off] : 0;
        __syncthreads();
        buf[t] += v;
        __syncthreads();
    }
    if (t < n) cbase[t] = (t == 0) ? 0 : buf[t - 1];
}

__global__ void scan_final(const int* __restrict__ cnt, const int* __restrict__ cbase,
                           int* __restrict__ cursor) {
    __shared__ int buf[256];
    int t = threadIdx.x, b = blockIdx.x;
    int v = cnt[b * 256 + t];
    buf[t] = v;
    __syncthreads();
    for (int off = 1; off < 256; off <<= 1) {
        int u = (t >= off) ? buf[t - off] : 0;
        __syncthreads();
        buf[t] += u;
        __syncthreads();
    }
    cursor[b * 256 + t] = cbase[b] + buf[t] - v;  // exclusive
}

__global__ void scatter_perm(const int* __restrict__ ei, int E,
                             int* __restrict__ cursor, int* __restrict__ perm) {
    int e = blockIdx.x * 256 + threadIdx.x;
    if (e < E) {
        int d = ei[E + e];
        int p = atomicAdd(&cursor[d], 1);
        perm[p] = e;
    }
}

// ---------- fused edgeconv: 64 dst-sorted edges per block, 4 waves ----------
template <int CIN, int COUT>
__launch_bounds__(256, 4) __global__
void edge_mfma(const float* __restrict__ xin, int bs_in,
               const int* __restrict__ inv,
               const int* __restrict__ ei, const int* __restrict__ perm, int E,
               const _Float16* __restrict__ W1s, const float* __restrict__ b1,
               const _Float16* __restrict__ W2s, const float* __restrict__ b2,
               const float* __restrict__ g, const float* __restrict__ bt,
               float* __restrict__ out, int bs_out) {
    constexpr int K1 = 2 * CIN;
    constexpr int FPITCH = K1 + 8;   // halfs; row stride multiple of 16B
    constexpr int HPITCH = COUT + 8; // halfs
    constexpr int NPW = COUT / 4;
    constexpr int NT = NPW / 16;
    constexpr int RHALF = (64 * FPITCH > 2 * 64 * HPITCH) ? 64 * FPITCH : 2 * 64 * HPITCH;

    __shared__ __align__(16) _Float16 region[RHALF];
    __shared__ int dstl[64];

    _Float16* featL = region;                   // gather..GEMM1
    _Float16* h1L   = region;                   // [0 : 64*HPITCH) after B2
    _Float16* vnL   = region + 64 * HPITCH;     // [64*HPITCH : 2*64*HPITCH)

    const int t = threadIdx.x;
    const int eb = blockIdx.x * 64;
    const int b = eb / E;
    const int e0 = eb - b * E;

    // ---- gather: 4 threads per edge (dst-sorted order) ----
    {
        const int m = t >> 2, l4 = t & 3;
        const int edge = perm[e0 + m];
        int s = ei[edge], d = ei[E + edge];
        if (l4 == 0) dstl[m] = d;
        int si = s, di = d;
        if (inv) { si = inv[s]; di = inv[d]; }
        const float* base = xin + (size_t)b * bs_in;
        #pragma unroll
        for (int i = 0; i < CIN / 16; ++i) {
            const int k4 = i * 4 + l4;
            f32x4 xd4 = {0.f, 0.f, 0.f, 0.f};
            f32x4 xs4 = {0.f, 0.f, 0.f, 0.f};
            if (di >= 0) xd4 = *(const f32x4*)(base + (size_t)di * CIN + k4 * 4);
            if (si >= 0) xs4 = *(const f32x4*)(base + (size_t)si * CIN + k4 * 4);
            half4v hd, hs;
            #pragma unroll
            for (int c = 0; c < 4; ++c) {
                hd[c] = (_Float16)xd4[c];
                hs[c] = (_Float16)(xs4[c] - xd4[c]);
            }
            *(half4v*)(featL + m * FPITCH + k4 * 4) = hd;
            *(half4v*)(featL + m * FPITCH + CIN + k4 * 4) = hs;
        }
    }
    __syncthreads();  // B1: feat ready

    const int wv = t >> 6, lane = t & 63;
    const int q = lane >> 4, lm = lane & 15;
    const int n0 = wv * NPW;
    const f32x4 zero4 = {0.f, 0.f, 0.f, 0.f};

    f32x4 acc[4][NT];
    #pragma unroll
    for (int mt = 0; mt < 4; ++mt)
        #pragma unroll
        for (int nt = 0; nt < NT; ++nt) acc[mt][nt] = zero4;

    // ---- GEMM1 ----
    #pragma unroll
    for (int kt = 0; kt < K1 / 32; ++kt) {
        half8 a[4];
        #pragma unroll
        for (int mt = 0; mt < 4; ++mt)
            a[mt] = *(const half8*)(featL + (mt * 16 + lm) * FPITCH + kt * 32 + q * 8);
        #pragma unroll
        for (int nt = 0; nt < NT; ++nt) {
            half8 bf = *(const half8*)(W1s + ((size_t)(kt * (COUT / 16) + wv * NT + nt) * 64 + lane) * 8);
            #pragma unroll
            for (int mt = 0; mt < 4; ++mt)
                acc[mt][nt] = __builtin_amdgcn_mfma_f32_16x16x32_f16(a[mt], bf, acc[mt][nt], 0, 0, 0);
        }
    }
    __syncthreads();  // B2: all waves done reading feat -> h1 may overwrite it

    #pragma unroll
    for (int nt = 0; nt < NT; ++nt) {
        const float b1v = b1[n0 + nt * 16 + lm];
        #pragma unroll
        for (int mt = 0; mt < 4; ++mt)
            #pragma unroll
            for (int r = 0; r < 4; ++r)
                h1L[(mt * 16 + q * 4 + r) * HPITCH + n0 + nt * 16 + lm] =
                    (_Float16)fmaxf(acc[mt][nt][r] + b1v, 0.f);
    }
    __syncthreads();  // B3: h1 ready

    // ---- GEMM2 ----
    #pragma unroll
    for (int mt = 0; mt < 4; ++mt)
        #pragma unroll
        for (int nt = 0; nt < NT; ++nt) acc[mt][nt] = zero4;

    #pragma unroll
    for (int kt = 0; kt < COUT / 32; ++kt) {
        half8 a[4];
        #pragma unroll
        for (int mt = 0; mt < 4; ++mt)
            a[mt] = *(const half8*)(h1L + (mt * 16 + lm) * HPITCH + kt * 32 + q * 8);
        #pragma unroll
        for (int nt = 0; nt < NT; ++nt) {
            half8 bf = *(const half8*)(W2s + ((size_t)(kt * (COUT / 16) + wv * NT + nt) * 64 + lane) * 8);
            #pragma unroll
            for (int mt = 0; mt < 4; ++mt)
                acc[mt][nt] = __builtin_amdgcn_mfma_f32_16x16x32_f16(a[mt], bf, acc[mt][nt], 0, 0, 0);
        }
    }

    // write v (pre-LN, fp16) — region disjoint from h1; feat dead since B2
    #pragma unroll
    for (int nt = 0; nt < NT; ++nt) {
        const float b2v = b2[n0 + nt * 16 + lm];
        #pragma unroll
        for (int mt = 0; mt < 4; ++mt)
            #pragma unroll
            for (int r = 0; r < 4; ++r)
                vnL[(mt * 16 + q * 4 + r) * HPITCH + n0 + nt * 16 + lm] =
                    (_Float16)(acc[mt][nt][r] + b2v);
    }
    __syncthreads();  // B4: vn + dstl ready

    // ---- LN + run-aggregated coalesced atomic scatter ----
    // wave wv2 owns rows [wv2*16, wv2*16+16); dst-sorted => runs aggregate in regs
    {
        const int wv2 = t >> 6, l2 = t & 63;
        const int rbase = wv2 * 16;
        if constexpr (COUT == 128) {
            const f32x2 gv = *(const f32x2*)(g + 2 * l2);
            const f32x2 bv = *(const f32x2*)(bt + 2 * l2);
            float rs0 = 0.f, rs1 = 0.f;
            #pragma unroll
            for (int i = 0; i < 16; ++i) {
                const int m = rbase + i;
                half2v h2 = *(const half2v*)(vnL + m * HPITCH + 2 * l2);
                float v0 = (float)h2[0], v1 = (float)h2[1];
                float s = v0 + v1, s2 = v0 * v0 + v1 * v1;
                #pragma unroll
                for (int off = 1; off < 64; off <<= 1) {
                    s  += __shfl_xor(s, off, 64);
                    s2 += __shfl_xor(s2, off, 64);
                }
                const float mu = s * (1.f / COUT);
                const float var = s2 * (1.f / COUT) - mu * mu;
                const float rstd = rsqrtf(var + 1e-5f);
                rs0 += (v0 - mu) * rstd * gv[0] + bv[0];
                rs1 += (v1 - mu) * rstd * gv[1] + bv[1];
                const int d = dstl[m];
                const bool flush = (i == 15) || (dstl[m + 1] != d);
                if (flush) {
                    float* ob = out + (size_t)b * bs_out + (size_t)d * COUT;
                    atomicAdd(ob + 2 * l2, rs0);
                    atomicAdd(ob + 2 * l2 + 1, rs1);
                    rs0 = 0.f; rs1 = 0.f;
                }
            }
        } else {
            const float gv = g[l2];
            const float bv = bt[l2];
            float rs = 0.f;
            #pragma unroll
            for (int i = 0; i < 16; ++i) {
                const int m = rbase + i;
                float v0 = (float)vnL[m * HPITCH + l2];
                float s = v0, s2 = v0 * v0;
                #pragma unroll
                for (int off = 1; off < 64; off <<= 1) {
                    s  += __shfl_xor(s, off, 64);
                    s2 += __shfl_xor(s2, off, 64);
                }
                const float mu = s * (1.f / COUT);
                const float var = s2 * (1.f / COUT) - mu * mu;
                const float rstd = rsqrtf(var + 1e-5f);
                rs += (v0 - mu) * rstd * gv + bv;
                const int d = dstl[m];
                const bool flush = (i == 15) || (dstl[m + 1] != d);
                if (flush) {
                    atomicAdd(out + (size_t)b * bs_out + (size_t)d * COUT + l2, rs);
                    rs = 0.f;
                }
            }
        }
    }
}

__global__ void leaky_kernel(float* __restrict__ out, int n4) {
    int i = blockIdx.x * blockDim.x + threadIdx.x;
    if (i < n4) {
        f32x4 v = ((f32x4*)out)[i];
        #pragma unroll
        for (int c = 0; c < 4; ++c) v[c] = v[c] > 0.f ? v[c] : 0.01f * v[c];
        ((f32x4*)out)[i] = v;
    }
}

extern "C" void kernel_launch(void* const* d_in, const int* in_sizes, int n_in,
                              void* d_out, int out_size, void* d_ws, size_t ws_size,
                              hipStream_t stream) {
    const float* x    = (const float*)d_in[0];
    const int*   idx  = (const int*)d_in[1];
    const int*   ei_c = (const int*)d_in[2];
    const int*   ei_f = (const int*)d_in[3];
    const float* sW1 = (const float*)d_in[4];
    const float* sb1 = (const float*)d_in[5];
    const float* sW2 = (const float*)d_in[6];
    const float* sb2 = (const float*)d_in[7];
    const float* sg  = (const float*)d_in[8];
    const float* sbt = (const float*)d_in[9];
    const float* aW1 = (const float*)d_in[10];
    const float* ab1 = (const float*)d_in[11];
    const float* aW2 = (const float*)d_in[12];
    const float* ab2 = (const float*)d_in[13];
    const float* ag  = (const float*)d_in[14];
    const float* abt = (const float*)d_in[15];
    const float* bW1 = (const float*)d_in[16];
    const float* bb1 = (const float*)d_in[17];
    const float* bW2 = (const float*)d_in[18];
    const float* bb2 = (const float*)d_in[19];
    const float* bg  = (const float*)d_in[20];
    const float* bbt = (const float*)d_in[21];

    float* out = (float*)d_out;

    // ---- ws layout ----
    char* ws = (char*)d_ws;
    int*   inv    = (int*)ws;                                ws += (size_t)N_F * 4;
    float* h_a    = (float*)ws;                              ws += (size_t)NB * N_C * 64 * 4;
    int*   perm_f = (int*)ws;                                ws += (size_t)E_F * 4;
    int*   perm_c = (int*)ws;                                ws += (size_t)E_C * 4;
    int*   cnt    = (int*)ws;                                ws += (size_t)N_F * 4;
    int*   cursor = (int*)ws;                                ws += (size_t)N_F * 4;
    int*   csum   = (int*)ws;                                ws += 256 * 4;
    int*   cbase  = (int*)ws;                                ws += 256 * 4;
    _Float16* sW1s = (_Float16*)ws;                          ws += 256 * 128 * 2;
    _Float16* sW2s = (_Float16*)ws;                          ws += 128 * 128 * 2;
    _Float16* aW1s = (_Float16*)ws;                          ws += 256 * 64 * 2;
    _Float16* aW2s = (_Float16*)ws;                          ws += 64 * 64 * 2;
    _Float16* bW1s = (_Float16*)ws;                          ws += 128 * 128 * 2;
    _Float16* bW2s = (_Float16*)ws;                          ws += 128 * 128 * 2;

    hipMemsetAsync(inv, 0xFF, (size_t)N_F * 4, stream);
    hipMemsetAsync(h_a, 0, (size_t)NB * N_C * 64 * 4, stream);
    hipMemsetAsync(d_out, 0, (size_t)out_size * 4, stream);

    build_inv<<<N_C / 256, 256, 0, stream>>>(idx, inv, N_C);

    swizzle_w<<<(256 * 128 + 255) / 256, 256, 0, stream>>>(sW1, sW1s, 256, 128);
    swizzle_w<<<(128 * 128 + 255) / 256, 256, 0, stream>>>(sW2, sW2s, 128, 128);
    swizzle_w<<<(256 * 64 + 255) / 256, 256, 0, stream>>>(aW1, aW1s, 256, 64);
    swizzle_w<<<(64 * 64 + 255) / 256, 256, 0, stream>>>(aW2, aW2s, 64, 64);
    swizzle_w<<<(128 * 128 + 255) / 256, 256, 0, stream>>>(bW1, bW1s, 128, 128);
    swizzle_w<<<(128 * 128 + 255) / 256, 256, 0, stream>>>(bW2, bW2s, 128, 128);

    // ---- sort ei_f by dst (N_F bins) ----
    hipMemsetAsync(cnt, 0, (size_t)N_F * 4, stream);
    hist_dst<<<E_F / 256, 256, 0, stream>>>(ei_f, E_F, cnt);
    scan_chunk_sums<<<N_F / 256, 256, 0, stream>>>(cnt, csum);
    scan_base<<<1, 256, 0, stream>>>(csum, cbase, N_F / 256);
    scan_final<<<N_F / 256, 256, 0, stream>>>(cnt, cbase, cursor);
    scatter_perm<<<E_F / 256, 256, 0, stream>>>(ei_f, E_F, cursor, perm_f);

    // ---- sort ei_c by dst (N_C bins) ----
    hipMemsetAsync(cnt, 0, (size_t)N_C * 4, stream);
    hist_dst<<<E_C / 256, 256, 0, stream>>>(ei_c, E_C, cnt);
    scan_chunk_sums<<<N_C / 256, 256, 0, stream>>>(cnt, csum);
    scan_base<<<1, 256, 0, stream>>>(csum, cbase, N_C / 256);
    scan_final<<<N_C / 256, 256, 0, stream>>>(cnt, cbase, cursor);
    scatter_perm<<<E_C / 256, 256, 0, stream>>>(ei_c, E_C, cursor, perm_c);

    // skip = edgeconv(unpool(x), ei_f, s-params) -> out
    edge_mfma<128, 128><<<NB * E_F / 64, 256, 0, stream>>>(
        x, N_C * 128, inv, ei_f, perm_f, E_F, sW1s, sb1, sW2s, sb2, sg, sbt, out, N_F * 128);

    // h_a = edgeconv(x, ei_c, a-params)
    edge_mfma<128, 64><<<NB * E_C / 64, 256, 0, stream>>>(
        x, N_C * 128, nullptr, ei_c, perm_c, E_C, aW1s, ab1, aW2s, ab2, ag, abt, h_a, N_C * 64);

    // out += edgeconv(unpool(h_a), ei_f, b-params)
    edge_mfma<64, 128><<<NB * E_F / 64, 256, 0, stream>>>(
        h_a, N_C * 64, inv, ei_f, perm_f, E_F, bW1s, bb1, bW2s, bb2, bg, bbt, out, N_F * 128);

    leaky_kernel<<<(NB * N_F * 128 / 4 + 255) / 256, 256, 0, stream>>>(out, NB * N_F * 128 / 4);
}

// Round 4
// 532.886 us; speedup vs baseline: 10.1091x; 1.1722x over previous
//
#include <hip/hip_runtime.h>

typedef _Float16 half8  __attribute__((ext_vector_type(8)));
typedef _Float16 half4v __attribute__((ext_vector_type(4)));
typedef _Float16 half2v __attribute__((ext_vector_type(2)));
typedef float    f32x4  __attribute__((ext_vector_type(4)));
typedef float    f32x2  __attribute__((ext_vector_type(2)));
typedef int      i32x4  __attribute__((ext_vector_type(4)));

#define NB 2
#define N_C 16384
#define N_F 65536
#define E_C 65536
#define E_F 262144

// ---------------- fused clear: out=0, h_a=0, inv=-1, cnt=0 ----------------
#define OUT4  ((size_t)NB * N_F * 128 / 4)         // 4,194,304
#define HA4   ((size_t)NB * N_C * 64 / 4)          // 524,288
#define INV4  ((size_t)N_F / 4)                    // 16,384
#define CNT4  ((size_t)(N_F + N_C) / 4)            // 20,480
#define CLR4  (OUT4 + HA4 + INV4 + CNT4)

__global__ void clear_all(float* __restrict__ out, float* __restrict__ h_a,
                          int* __restrict__ inv, int* __restrict__ cnt) {
    size_t i = (size_t)blockIdx.x * 256 + threadIdx.x;
    if (i >= CLR4) return;
    const i32x4 z = {0, 0, 0, 0};
    const i32x4 m1 = {-1, -1, -1, -1};
    if (i < OUT4) ((i32x4*)out)[i] = z;
    else if (i < OUT4 + HA4) ((i32x4*)h_a)[i - OUT4] = z;
    else if (i < OUT4 + HA4 + INV4) ((i32x4*)inv)[i - OUT4 - HA4] = m1;
    else ((i32x4*)cnt)[i - OUT4 - HA4 - INV4] = z;
}

// ---------------- fused setup: build_inv + 6 weight swizzles + 2 hists ----------------
__device__ inline void swizzle_dev(const float* __restrict__ W, _Float16* __restrict__ Ws,
                                   int N, int o) {
    int j = o & 7;
    int lane = (o >> 3) & 63;
    int frag = o >> 9;
    int ntiles = N >> 4;
    int nt = frag % ntiles;
    int kt = frag / ntiles;
    int k = kt * 32 + (lane >> 4) * 8 + j;
    int n = nt * 16 + (lane & 15);
    Ws[o] = (_Float16)W[k * N + n];
}

// block ranges: [0,64) inv | [64,192) sW1 | [192,256) sW2 | [256,320) aW1
//               [320,336) aW2 | [336,400) bW1 | [400,464) bW2 | [464,1488) hist_f | [1488,1744) hist_c
__global__ void setup_all(const int* __restrict__ idx, int* __restrict__ inv,
                          const float* sW1, const float* sW2, const float* aW1,
                          const float* aW2, const float* bW1, const float* bW2,
                          _Float16* sW1s, _Float16* sW2s, _Float16* aW1s,
                          _Float16* aW2s, _Float16* bW1s, _Float16* bW2s,
                          const int* __restrict__ ei_f, const int* __restrict__ ei_c,
                          int* __restrict__ cnt) {
    const int bb = blockIdx.x, t = threadIdx.x;
    if (bb < 64) {
        int i = bb * 256 + t;
        inv[idx[i]] = i;
    } else if (bb < 192) {
        swizzle_dev(sW1, sW1s, 128, (bb - 64) * 256 + t);
    } else if (bb < 256) {
        swizzle_dev(sW2, sW2s, 128, (bb - 192) * 256 + t);
    } else if (bb < 320) {
        swizzle_dev(aW1, aW1s, 64, (bb - 256) * 256 + t);
    } else if (bb < 336) {
        swizzle_dev(aW2, aW2s, 64, (bb - 320) * 256 + t);
    } else if (bb < 400) {
        swizzle_dev(bW1, bW1s, 128, (bb - 336) * 256 + t);
    } else if (bb < 464) {
        swizzle_dev(bW2, bW2s, 128, (bb - 400) * 256 + t);
    } else if (bb < 1488) {
        int e = (bb - 464) * 256 + t;
        atomicAdd(&cnt[ei_f[E_F + e]], 1);
    } else {
        int e = (bb - 1488) * 256 + t;
        atomicAdd(&cnt[N_F + ei_c[E_C + e]], 1);
    }
}

// ---------------- counting sort (f bins [0,N_F), c bins [N_F,N_F+N_C)) ----------------
__global__ void scan1(const int* __restrict__ cnt, int* __restrict__ csum) {
    __shared__ int red[4];
    int v = cnt[blockIdx.x * 256 + threadIdx.x];
    #pragma unroll
    for (int off = 32; off >= 1; off >>= 1) v += __shfl_xor(v, off, 64);
    if ((threadIdx.x & 63) == 0) red[threadIdx.x >> 6] = v;
    __syncthreads();
    if (threadIdx.x == 0) csum[blockIdx.x] = red[0] + red[1] + red[2] + red[3];
}

__global__ void scan2(const int* __restrict__ csum, int* __restrict__ cbase) {
    __shared__ int buf[256];
    const int t = threadIdx.x;
    int v = csum[t];
    buf[t] = v;
    __syncthreads();
    for (int off = 1; off < 256; off <<= 1) {
        int u = (t >= off) ? buf[t - off] : 0;
        __syncthreads();
        buf[t] += u;
        __syncthreads();
    }
    cbase[t] = buf[t] - v;
    __syncthreads();
    int v2 = (t < 64) ? csum[256 + t] : 0;
    buf[t] = v2;
    __syncthreads();
    for (int off = 1; off < 64; off <<= 1) {
        int u = (t >= off) ? buf[t - off] : 0;
        __syncthreads();
        buf[t] += u;
        __syncthreads();
    }
    if (t < 64) cbase[256 + t] = buf[t] - v2;
}

__global__ void scan3(const int* __restrict__ cnt, const int* __restrict__ cbase,
                      int* __restrict__ cursor) {
    __shared__ int buf[256];
    const int t = threadIdx.x, bb = blockIdx.x;
    int v = cnt[bb * 256 + t];
    buf[t] = v;
    __syncthreads();
    for (int off = 1; off < 256; off <<= 1) {
        int u = (t >= off) ? buf[t - off] : 0;
        __syncthreads();
        buf[t] += u;
        __syncthreads();
    }
    cursor[bb * 256 + t] = cbase[bb] + buf[t] - v;
}

__global__ void scatter2(const int* __restrict__ ei_f, const int* __restrict__ ei_c,
                         int* __restrict__ cursor,
                         int* __restrict__ perm_f, int* __restrict__ perm_c) {
    const int bb = blockIdx.x, t = threadIdx.x;
    if (bb < 1024) {
        int e = bb * 256 + t;
        int d = ei_f[E_F + e];
        int p = atomicAdd(&cursor[d], 1);
        perm_f[p] = e;
    } else {
        int e = (bb - 1024) * 256 + t;
        int d = ei_c[E_C + e];
        int p = atomicAdd(&cursor[N_F + d], 1);
        perm_c[p] = e;
    }
}

// ---------------- fused edgeconv: 64 dst-sorted edges per block, 4 waves ----------------
template <int CIN, int COUT>
__launch_bounds__(256, 4) __global__
void edge_mfma(const float* __restrict__ xin, int bs_in,
               const int* __restrict__ inv,
               const int* __restrict__ ei, const int* __restrict__ perm, int E,
               const _Float16* __restrict__ W1s, const float* __restrict__ b1,
               const _Float16* __restrict__ W2s, const float* __restrict__ b2,
               const float* __restrict__ g, const float* __restrict__ bt,
               float* __restrict__ out, int bs_out) {
    constexpr int K1 = 2 * CIN;
    constexpr int FPITCH = K1 + 8;   // halfs; row stride multiple of 16B
    constexpr int HPITCH = COUT + 8; // halfs
    constexpr int NPW = COUT / 4;
    constexpr int NT = NPW / 16;
    constexpr int RHALF = (64 * FPITCH > 2 * 64 * HPITCH) ? 64 * FPITCH : 2 * 64 * HPITCH;

    __shared__ __align__(16) _Float16 region[RHALF];
    __shared__ int dstl[64];
    __shared__ float muL[64];
    __shared__ float rsL[64];

    _Float16* featL = region;                   // gather..GEMM1
    _Float16* h1L   = region;                   // [0 : 64*HPITCH) after B2
    _Float16* vnL   = region + 64 * HPITCH;     // [64*HPITCH : 2*64*HPITCH)

    const int t = threadIdx.x;
    const int eb = blockIdx.x * 64;
    const int b = eb / E;
    const int e0 = eb - b * E;

    // ---- gather: 4 threads per edge (dst-sorted order) ----
    {
        const int m = t >> 2, l4 = t & 3;
        const int edge = perm[e0 + m];
        int s = ei[edge], d = ei[E + edge];
        if (l4 == 0) dstl[m] = d;
        int si = s, di = d;
        if (inv) { si = inv[s]; di = inv[d]; }
        const float* base = xin + (size_t)b * bs_in;
        #pragma unroll
        for (int i = 0; i < CIN / 16; ++i) {
            const int k4 = i * 4 + l4;
            f32x4 xd4 = {0.f, 0.f, 0.f, 0.f};
            f32x4 xs4 = {0.f, 0.f, 0.f, 0.f};
            if (di >= 0) xd4 = *(const f32x4*)(base + (size_t)di * CIN + k4 * 4);
            if (si >= 0) xs4 = *(const f32x4*)(base + (size_t)si * CIN + k4 * 4);
            half4v hd, hs;
            #pragma unroll
            for (int c = 0; c < 4; ++c) {
                hd[c] = (_Float16)xd4[c];
                hs[c] = (_Float16)(xs4[c] - xd4[c]);
            }
            *(half4v*)(featL + m * FPITCH + k4 * 4) = hd;
            *(half4v*)(featL + m * FPITCH + CIN + k4 * 4) = hs;
        }
    }
    __syncthreads();  // B1: feat ready

    const int wv = t >> 6, lane = t & 63;
    const int q = lane >> 4, lm = lane & 15;
    const int n0 = wv * NPW;
    const f32x4 zero4 = {0.f, 0.f, 0.f, 0.f};

    f32x4 acc[4][NT];
    #pragma unroll
    for (int mt = 0; mt < 4; ++mt)
        #pragma unroll
        for (int nt = 0; nt < NT; ++nt) acc[mt][nt] = zero4;

    // ---- GEMM1 ----
    #pragma unroll
    for (int kt = 0; kt < K1 / 32; ++kt) {
        half8 a[4];
        #pragma unroll
        for (int mt = 0; mt < 4; ++mt)
            a[mt] = *(const half8*)(featL + (mt * 16 + lm) * FPITCH + kt * 32 + q * 8);
        #pragma unroll
        for (int nt = 0; nt < NT; ++nt) {
            half8 bf = *(const half8*)(W1s + ((size_t)(kt * (COUT / 16) + wv * NT + nt) * 64 + lane) * 8);
            #pragma unroll
            for (int mt = 0; mt < 4; ++mt)
                acc[mt][nt] = __builtin_amdgcn_mfma_f32_16x16x32_f16(a[mt], bf, acc[mt][nt], 0, 0, 0);
        }
    }
    __syncthreads();  // B2: all waves done reading feat -> h1 may overwrite it

    #pragma unroll
    for (int nt = 0; nt < NT; ++nt) {
        const float b1v = b1[n0 + nt * 16 + lm];
        #pragma unroll
        for (int mt = 0; mt < 4; ++mt)
            #pragma unroll
            for (int r = 0; r < 4; ++r)
                h1L[(mt * 16 + q * 4 + r) * HPITCH + n0 + nt * 16 + lm] =
                    (_Float16)fmaxf(acc[mt][nt][r] + b1v, 0.f);
    }
    __syncthreads();  // B3: h1 ready

    // ---- GEMM2 ----
    #pragma unroll
    for (int mt = 0; mt < 4; ++mt)
        #pragma unroll
        for (int nt = 0; nt < NT; ++nt) acc[mt][nt] = zero4;

    #pragma unroll
    for (int kt = 0; kt < COUT / 32; ++kt) {
        half8 a[4];
        #pragma unroll
        for (int mt = 0; mt < 4; ++mt)
            a[mt] = *(const half8*)(h1L + (mt * 16 + lm) * HPITCH + kt * 32 + q * 8);
        #pragma unroll
        for (int nt = 0; nt < NT; ++nt) {
            half8 bf = *(const half8*)(W2s + ((size_t)(kt * (COUT / 16) + wv * NT + nt) * 64 + lane) * 8);
            #pragma unroll
            for (int mt = 0; mt < 4; ++mt)
                acc[mt][nt] = __builtin_amdgcn_mfma_f32_16x16x32_f16(a[mt], bf, acc[mt][nt], 0, 0, 0);
        }
    }

    // write v = acc + b2 (pre-LN, fp16) — region disjoint from h1; feat dead since B2
    #pragma unroll
    for (int nt = 0; nt < NT; ++nt) {
        const float b2v = b2[n0 + nt * 16 + lm];
        #pragma unroll
        for (int mt = 0; mt < 4; ++mt)
            #pragma unroll
            for (int r = 0; r < 4; ++r)
                vnL[(mt * 16 + q * 4 + r) * HPITCH + n0 + nt * 16 + lm] =
                    (_Float16)(acc[mt][nt][r] + b2v);
    }
    __syncthreads();  // B4: vn + dstl ready

    // ---- parallel LN stats: 4 threads per row, 2 shuffle levels ----
    {
        const int m = t >> 2, p = t & 3;
        constexpr int CPT = COUT / 4;  // cols per thread
        float s = 0.f, s2 = 0.f;
        #pragma unroll
        for (int c = 0; c < CPT / 8; ++c) {
            half8 h8 = *(const half8*)(vnL + m * HPITCH + p * CPT + c * 8);
            #pragma unroll
            for (int j = 0; j < 8; ++j) {
                float v = (float)h8[j];
                s += v;
                s2 += v * v;
            }
        }
        s += __shfl_xor(s, 1, 64);  s2 += __shfl_xor(s2, 1, 64);
        s += __shfl_xor(s, 2, 64);  s2 += __shfl_xor(s2, 2, 64);
        if (p == 0) {
            float mu = s * (1.f / COUT);
            muL[m] = mu;
            rsL[m] = rsqrtf(s2 * (1.f / COUT) - mu * mu + 1e-5f);
        }
    }
    __syncthreads();  // B5: stats ready

    // ---- apply LN + run-aggregated coalesced atomic scatter (no shuffles) ----
    {
        const int wv2 = t >> 6, l2 = t & 63;
        const int rbase = wv2 * 16;
        if constexpr (COUT == 128) {
            const f32x2 gv = *(const f32x2*)(g + 2 * l2);
            const f32x2 bv = *(const f32x2*)(bt + 2 * l2);
            float rs0 = 0.f, rs1 = 0.f;
            #pragma unroll
            for (int i = 0; i < 16; ++i) {
                const int m = rbase + i;
                half2v h2 = *(const half2v*)(vnL + m * HPITCH + 2 * l2);
                const float mu = muL[m], rstd = rsL[m];
                rs0 += ((float)h2[0] - mu) * rstd * gv[0] + bv[0];
                rs1 += ((float)h2[1] - mu) * rstd * gv[1] + bv[1];
                const int d = dstl[m];
                if (i == 15 || dstl[m + 1] != d) {
                    float* ob = out + (size_t)b * bs_out + (size_t)d * COUT + 2 * l2;
                    atomicAdd(ob, rs0);
                    atomicAdd(ob + 1, rs1);
                    rs0 = 0.f;
                    rs1 = 0.f;
                }
            }
        } else {
            const float gv = g[l2];
            const float bv = bt[l2];
            float rs = 0.f;
            #pragma unroll
            for (int i = 0; i < 16; ++i) {
                const int m = rbase + i;
                const float mu = muL[m], rstd = rsL[m];
                float v0 = (float)vnL[m * HPITCH + l2];
                rs += (v0 - mu) * rstd * gv + bv;
                const int d = dstl[m];
                if (i == 15 || dstl[m + 1] != d) {
                    atomicAdd(out + (size_t)b * bs_out + (size_t)d * COUT + l2, rs);
                    rs = 0.f;
                }
            }
        }
    }
}

__global__ void leaky_kernel(float* __restrict__ out, int n4) {
    int i = blockIdx.x * blockDim.x + threadIdx.x;
    if (i < n4) {
        f32x4 v = ((f32x4*)out)[i];
        #pragma unroll
        for (int c = 0; c < 4; ++c) v[c] = v[c] > 0.f ? v[c] : 0.01f * v[c];
        ((f32x4*)out)[i] = v;
    }
}

extern "C" void kernel_launch(void* const* d_in, const int* in_sizes, int n_in,
                              void* d_out, int out_size, void* d_ws, size_t ws_size,
                              hipStream_t stream) {
    const float* x    = (const float*)d_in[0];
    const int*   idx  = (const int*)d_in[1];
    const int*   ei_c = (const int*)d_in[2];
    const int*   ei_f = (const int*)d_in[3];
    const float* sW1 = (const float*)d_in[4];
    const float* sb1 = (const float*)d_in[5];
    const float* sW2 = (const float*)d_in[6];
    const float* sb2 = (const float*)d_in[7];
    const float* sg  = (const float*)d_in[8];
    const float* sbt = (const float*)d_in[9];
    const float* aW1 = (const float*)d_in[10];
    const float* ab1 = (const float*)d_in[11];
    const float* aW2 = (const float*)d_in[12];
    const float* ab2 = (const float*)d_in[13];
    const float* ag  = (const float*)d_in[14];
    const float* abt = (const float*)d_in[15];
    const float* bW1 = (const float*)d_in[16];
    const float* bb1 = (const float*)d_in[17];
    const float* bW2 = (const float*)d_in[18];
    const float* bb2 = (const float*)d_in[19];
    const float* bg  = (const float*)d_in[20];
    const float* bbt = (const float*)d_in[21];

    float* out = (float*)d_out;

    // ---- ws layout ----
    char* ws = (char*)d_ws;
    int*   inv    = (int*)ws;                                ws += (size_t)N_F * 4;
    float* h_a    = (float*)ws;                              ws += (size_t)NB * N_C * 64 * 4;
    int*   perm_f = (int*)ws;                                ws += (size_t)E_F * 4;
    int*   perm_c = (int*)ws;                                ws += (size_t)E_C * 4;
    int*   cnt    = (int*)ws;                                ws += (size_t)(N_F + N_C) * 4;
    int*   cursor = (int*)ws;                                ws += (size_t)(N_F + N_C) * 4;
    int*   csum   = (int*)ws;                                ws += 320 * 4;
    int*   cbase  = (int*)ws;                                ws += 320 * 4;
    _Float16* sW1s = (_Float16*)ws;                          ws += 256 * 128 * 2;
    _Float16* sW2s = (_Float16*)ws;                          ws += 128 * 128 * 2;
    _Float16* aW1s = (_Float16*)ws;                          ws += 256 * 64 * 2;
    _Float16* aW2s = (_Float16*)ws;                          ws += 64 * 64 * 2;
    _Float16* bW1s = (_Float16*)ws;                          ws += 128 * 128 * 2;
    _Float16* bW2s = (_Float16*)ws;                          ws += 128 * 128 * 2;

    // 1) clear: out=0, h_a=0, inv=-1, cnt=0
    clear_all<<<(int)((CLR4 + 255) / 256), 256, 0, stream>>>(out, h_a, inv, cnt);

    // 2) setup: build_inv + all weight swizzles + both dst histograms
    setup_all<<<1744, 256, 0, stream>>>(idx, inv, sW1, sW2, aW1, aW2, bW1, bW2,
                                        sW1s, sW2s, aW1s, aW2s, bW1s, bW2s,
                                        ei_f, ei_c, cnt);

    // 3-6) counting sort both edge lists by dst
    scan1<<<320, 256, 0, stream>>>(cnt, csum);
    scan2<<<1, 256, 0, stream>>>(csum, cbase);
    scan3<<<320, 256, 0, stream>>>(cnt, cbase, cursor);
    scatter2<<<1280, 256, 0, stream>>>(ei_f, ei_c, cursor, perm_f, perm_c);

    // 7) skip = edgeconv(unpool(x), ei_f, s-params) -> out
    edge_mfma<128, 128><<<NB * E_F / 64, 256, 0, stream>>>(
        x, N_C * 128, inv, ei_f, perm_f, E_F, sW1s, sb1, sW2s, sb2, sg, sbt, out, N_F * 128);

    // 8) h_a = edgeconv(x, ei_c, a-params)
    edge_mfma<128, 64><<<NB * E_C / 64, 256, 0, stream>>>(
        x, N_C * 128, nullptr, ei_c, perm_c, E_C, aW1s, ab1, aW2s, ab2, ag, abt, h_a, N_C * 64);

    // 9) out += edgeconv(unpool(h_a), ei_f, b-params)
    edge_mfma<64, 128><<<NB * E_F / 64, 256, 0, stream>>>(
        h_a, N_C * 64, inv, ei_f, perm_f, E_F, bW1s, bb1, bW2s, bb2, bg, bbt, out, N_F * 128);

    // 10) leaky relu in place
    leaky_kernel<<<(NB * N_F * 128 / 4 + 255) / 256, 256, 0, stream>>>(out, NB * N_F * 128 / 4);
}